// Round 16
// baseline (346.658 us; speedup 1.0000x reference)
//
#include <hip/hip_runtime.h>

#define T_TOK 4096
#define DIN   1024
#define DOUT  1024
#define NEXP  8
#define HDIM  4096
#define RCAP  9216       // 8192 rows + 8 experts x <=127 pad (128-aligned)
#define MT128 80

typedef float f32x4 __attribute__((ext_vector_type(4)));
typedef short bf16x8 __attribute__((ext_vector_type(8)));
typedef unsigned short u16x4 __attribute__((ext_vector_type(4)));
typedef unsigned short u16x8 __attribute__((ext_vector_type(8)));

__device__ __forceinline__ float bf2f(unsigned short u) {
    union { unsigned int i; float f; } v; v.i = ((unsigned int)u) << 16; return v.f;
}
__device__ __forceinline__ unsigned short f2bf(float f) {
    union { unsigned int i; float f; } v; v.f = f;
    unsigned int r = v.i + 0x7FFFu + ((v.i >> 16) & 1u);
    return (unsigned short)(r >> 16);
}

// One wave per token: fp64 gating dots, softplus, top-2, softmax. NO atomics.
// (R14-proven standalone; R15 showed fusing this with convw costs ~55 us.)
__global__ __launch_bounds__(64) void gating_kernel(
    const float* __restrict__ x, const float* __restrict__ noise,
    const float* __restrict__ gw, const float* __restrict__ gb,
    const float* __restrict__ nw, const float* __restrict__ nb,
    float* __restrict__ wout,
    int* __restrict__ tok_e, float* __restrict__ tok_p)
{
    int t = blockIdx.x;
    int lane = threadIdx.x;
    const float* xr = x + (size_t)t * DIN;
    double ag[NEXP], an[NEXP];
#pragma unroll
    for (int e = 0; e < NEXP; ++e) { ag[e] = 0.0; an[e] = 0.0; }
    for (int d = lane; d < DIN; d += 64) {
        double xv = (double)xr[d];
        const f32x4* g4 = (const f32x4*)(gw + (size_t)d * NEXP);
        const f32x4* n4 = (const f32x4*)(nw + (size_t)d * NEXP);
        f32x4 ga = g4[0], gbv = g4[1], na = n4[0], nbv = n4[1];
#pragma unroll
        for (int j = 0; j < 4; ++j) {
            ag[j]     += xv * (double)ga[j];
            ag[4 + j] += xv * (double)gbv[j];
            an[j]     += xv * (double)na[j];
            an[4 + j] += xv * (double)nbv[j];
        }
    }
#pragma unroll
    for (int e = 0; e < NEXP; ++e) {
        double g = ag[e], n = an[e];
#pragma unroll
        for (int m = 32; m > 0; m >>= 1) { g += __shfl_xor(g, m); n += __shfl_xor(n, m); }
        ag[e] = g; an[e] = n;
    }
    double lg[NEXP];
#pragma unroll
    for (int e = 0; e < NEXP; ++e) {
        double z = an[e] + (double)nb[e];
        double sp = fmax(z, 0.0) + log1p(exp(-fabs(z)));
        lg[e] = ag[e] + (double)gb[e] + (double)noise[(size_t)t * NEXP + e] * sp;
    }
    int i0 = 0; double v0 = lg[0];
#pragma unroll
    for (int e = 1; e < NEXP; ++e) if (lg[e] > v0) { v0 = lg[e]; i0 = e; }
    int i1 = -1; double v1 = -1.0e300;
#pragma unroll
    for (int e = 0; e < NEXP; ++e) if (e != i0 && lg[e] > v1) { v1 = lg[e]; i1 = e; }
    double d1 = exp(v1 - v0);
    float p0 = (float)(1.0 / (1.0 + d1));
    float p1 = (float)(d1 / (1.0 + d1));
    if (lane < NEXP) {
        float wv = (lane == i0) ? p0 : ((lane == i1) ? p1 : 0.0f);
        wout[(size_t)t * NEXP + lane] = wv;
    }
    if (lane == 0) {
        tok_e[2 * t] = i0;     tok_e[2 * t + 1] = i1;
        tok_p[2 * t] = p0;     tok_p[2 * t + 1] = p1;
    }
}

// Deterministic slot assignment: block e scans tok_e[] in sequential order.
__global__ __launch_bounds__(256) void scan_kernel(
    const int* __restrict__ tok_e, int* __restrict__ tok_slot, int* __restrict__ cnt)
{
    __shared__ int wsum[4];
    int e = blockIdx.x;
    int tid = threadIdx.x;
    int wv = tid >> 6;
    int lane = tid & 63;
    int base = 0;
    for (int c = 0; c < 2 * T_TOK; c += 256) {
        int i = c + tid;
        int m = (tok_e[i] == e) ? 1 : 0;
        unsigned long long bal = __ballot(m);
        int before = __popcll(bal & ((1ull << lane) - 1ull));
        if (lane == 0) wsum[wv] = __popcll(bal);
        __syncthreads();
        int woff = 0;
#pragma unroll
        for (int w = 0; w < 4; ++w) if (w < wv) woff += wsum[w];
        if (m) tok_slot[i] = base + woff + before;
        int tot = wsum[0] + wsum[1] + wsum[2] + wsum[3];
        __syncthreads();
        base += tot;
    }
    if (tid == 0) cnt[e] = base;
}

// 128-row-aligned per-expert offsets + 128-row tile map.
__global__ void prefix_kernel(const int* __restrict__ cnt, int* __restrict__ poff,
                              int* __restrict__ t2e, int* __restrict__ trow)
{
    if (threadIdx.x != 0 || blockIdx.x != 0) return;
    int base = 0, a = 0;
    for (int e = 0; e < NEXP; ++e) {
        poff[e] = base;
        int c = cnt[e];
        int nt = (c + 127) >> 7;
        for (int i = 0; i < nt; ++i) { t2e[a] = e; trow[a] = base + (i << 7); ++a; }
        base += nt << 7;
    }
    for (; a < MT128; ++a) { t2e[a] = -1; trow[a] = 0; }
}

// Copy token row t (fp32) to its expert slot as bf16.
__global__ __launch_bounds__(256) void gather_kernel(
    const float* __restrict__ x, const int* __restrict__ tok_e,
    const int* __restrict__ tok_slot, const int* __restrict__ poff,
    unsigned short* __restrict__ Xg)
{
    int b = blockIdx.x;
    int t = b >> 1, k = b & 1;
    int e = tok_e[2 * t + k];
    int row = poff[e] + tok_slot[2 * t + k];
    int c = threadIdx.x << 2;
    f32x4 v = *(const f32x4*)(x + (size_t)t * DIN + c);
    u16x4 o;
#pragma unroll
    for (int j = 0; j < 4; ++j) o[j] = f2bf(v[j]);
    *(u16x4*)(Xg + (size_t)row * DIN + c) = o;
}

// Transpose+convert both W1 and W2 in ONE dispatch (R14-proven, ~5.5 TB/s —
// at the HBM ceiling for its 390 MB of traffic).
__global__ __launch_bounds__(256) void convw2x_kernel(
    const float* __restrict__ w1, unsigned short* __restrict__ W1t,
    const float* __restrict__ w2, unsigned short* __restrict__ W2t)
{
    __shared__ float tile[64][65];
    int e = blockIdx.x;
    int idx = blockIdx.y;
    const float* W; unsigned short* Wt; int K, N, k0, n0;
    if (idx < 1024) {
        W = w1; Wt = W1t; K = DIN; N = HDIM;
        k0 = (idx >> 6) << 6; n0 = (idx & 63) << 6;
    } else {
        int i2 = idx - 1024;
        W = w2; Wt = W2t; K = HDIM; N = DOUT;
        k0 = (i2 >> 4) << 6; n0 = (i2 & 15) << 6;
    }
    int tid = threadIdx.x;
    const float* src = W + ((size_t)e * K + k0) * N + n0;
    int r = tid >> 4, c4 = (tid & 15) << 2;
#pragma unroll
    for (int i = 0; i < 4; ++i) {
        f32x4 v = *(const f32x4*)(src + (size_t)(r + (i << 4)) * N + c4);
        *(f32x4*)(&tile[r + (i << 4)][c4]) = v;
    }
    __syncthreads();
    unsigned short* dst = Wt + ((size_t)e * N + n0) * K + k0;
#pragma unroll
    for (int i = 0; i < 2; ++i) {
        int u = (i << 8) + tid;          // 512 units of 16B
        int n = u >> 3, kk = (u & 7) << 3;
        u16x8 o;
#pragma unroll
        for (int q = 0; q < 8; ++q) o[q] = f2bf(tile[kk + q][n]);
        *(u16x8*)(dst + (size_t)n * K + kk) = o;
    }
}

// GEMM1: 128x256 tile, BK=64, 8 waves (R14-proven), single-buffer 48KB LDS,
// 2-barrier loop, BK=64 swizzle LDS[r*64 + ((k>>3 ^ (r&7))<<3) + (k&7)].
__global__ __launch_bounds__(512, 4) void gemm1_wide_kernel(
    const unsigned short* __restrict__ A,
    const unsigned short* __restrict__ Bt,
    unsigned short* __restrict__ C,
    const float* __restrict__ bias,
    const int* __restrict__ t2e, const int* __restrict__ trow)
{
    const int lda = DIN, ldb = DIN, N = HDIM;
    int cpx = gridDim.x >> 3;
    int wg = ((blockIdx.x & 7) * cpx) + (blockIdx.x >> 3);
    int tileid = wg >> 4;
    int nb = wg & 15;
    int e = t2e[tileid];
    if (e < 0) return;
    int row0 = trow[tileid];
    int n0 = nb << 8;

    __shared__ __align__(16) unsigned short As[128 * 64];
    __shared__ __align__(16) unsigned short Bs[256 * 64];

    int tid = threadIdx.x;
    int lane = tid & 63;
    int wv = tid >> 6;
    int wr = (wv >> 2) << 6;
    int wc = (wv & 3) << 6;

    const unsigned short* Ab = A + (size_t)row0 * lda;
    const unsigned short* Bb = Bt + ((size_t)e * N + n0) * ldb;

    f32x4 acc[4][4] = {};
    int hr = lane & 15;
    int q4 = lane >> 4;

    for (int kt = 0; kt < 16; ++kt) {
        __syncthreads();
        int kb = kt << 6;
#pragma unroll
        for (int i = 0; i < 2; ++i) {
            int u = (i << 9) + tid;
            int r = u >> 3, sp = u & 7;
            int col = ((sp ^ (r & 7)) << 3);
            __builtin_amdgcn_global_load_lds(
                (const __attribute__((address_space(1))) void*)(Ab + (size_t)r * lda + kb + col),
                (__attribute__((address_space(3))) void*)(&As[u << 3]), 16, 0, 0);
        }
#pragma unroll
        for (int i = 0; i < 4; ++i) {
            int u = (i << 9) + tid;
            int r = u >> 3, sp = u & 7;
            int col = ((sp ^ (r & 7)) << 3);
            __builtin_amdgcn_global_load_lds(
                (const __attribute__((address_space(1))) void*)(Bb + (size_t)r * ldb + kb + col),
                (__attribute__((address_space(3))) void*)(&Bs[u << 3]), 16, 0, 0);
        }
        __syncthreads();
#pragma unroll
        for (int kq = 0; kq < 2; ++kq) {
            int slog = (kq << 2) | q4;
            bf16x8 af[4], bfv[4];
#pragma unroll
            for (int m = 0; m < 4; ++m) {
                int r = wr + (m << 4) + hr;
                af[m] = *(const bf16x8*)(&As[(r << 6) + ((slog ^ (r & 7)) << 3)]);
            }
#pragma unroll
            for (int n = 0; n < 4; ++n) {
                int r = wc + (n << 4) + hr;
                bfv[n] = *(const bf16x8*)(&Bs[(r << 6) + ((slog ^ (r & 7)) << 3)]);
            }
#pragma unroll
            for (int m = 0; m < 4; ++m)
#pragma unroll
                for (int n = 0; n < 4; ++n)
                    acc[m][n] = __builtin_amdgcn_mfma_f32_16x16x32_bf16(af[m], bfv[n], acc[m][n], 0, 0, 0);
        }
    }

    int rq = q4 << 2;
    int cl = hr;
#pragma unroll
    for (int n = 0; n < 4; ++n) {
        int col = wc + (n << 4) + cl;
        float bv = bias[(size_t)e * N + n0 + col];
#pragma unroll
        for (int m = 0; m < 4; ++m) {
#pragma unroll
            for (int r = 0; r < 4; ++r) {
                int row = wr + (m << 4) + rq + r;
                float v = acc[m][n][r] + bv;
                v = fmaxf(v, 0.0f);
                C[(size_t)(row0 + row) * N + n0 + col] = f2bf(v);
            }
        }
    }
}

// GEMM2: 128x128 BK=64 kernel + split-K=2 (R15-proven: 1280 blocks, 5/CU).
__global__ __launch_bounds__(256, 4) void gemm2_sk_kernel(
    const unsigned short* __restrict__ A,    // H [RCAP][4096]
    const unsigned short* __restrict__ Bt,   // W2t [E][1024][4096]
    unsigned short* __restrict__ C0, unsigned short* __restrict__ C1,
    const float* __restrict__ bias,
    const int* __restrict__ t2e, const int* __restrict__ trow)
{
    const int lda = HDIM, ldb = HDIM, N = DOUT, KLEN = HDIM / 2;
    int cpx = gridDim.x >> 3;                // 160
    int wg = ((blockIdx.x & 7) * cpx) + (blockIdx.x >> 3);
    int tileid = wg >> 4;
    int low = wg & 15;
    int nb = low >> 1;
    int ks = low & 1;

    int e = t2e[tileid];
    if (e < 0) return;
    int row0 = trow[tileid];
    int n0 = nb << 7;
    int koff = ks * KLEN;
    unsigned short* C = ks ? C1 : C0;

    __shared__ __align__(16) unsigned short As[128 * 64];
    __shared__ __align__(16) unsigned short Bs[128 * 64];

    int tid = threadIdx.x;
    int lane = tid & 63;
    int wv = tid >> 6;
    int wr = (wv >> 1) << 6;
    int wc = (wv & 1) << 6;

    const unsigned short* Ab = A + (size_t)row0 * lda + koff;
    const unsigned short* Bb = Bt + ((size_t)e * N + n0) * ldb + koff;

    f32x4 acc[4][4] = {};

    int sr_lo = tid >> 3;
    int sp = tid & 7;
    int hr = lane & 15;
    int q4 = lane >> 4;

    for (int kt = 0; kt < KLEN / 64; ++kt) {
        __syncthreads();
        int kb = kt << 6;
#pragma unroll
        for (int i = 0; i < 4; ++i) {
            int r = (i << 5) + sr_lo;
            int col = ((sp ^ (r & 7)) << 3);
            int u = (i << 8) + tid;
            __builtin_amdgcn_global_load_lds(
                (const __attribute__((address_space(1))) void*)(Ab + (size_t)r * lda + kb + col),
                (__attribute__((address_space(3))) void*)(&As[u << 3]), 16, 0, 0);
            __builtin_amdgcn_global_load_lds(
                (const __attribute__((address_space(1))) void*)(Bb + (size_t)r * ldb + kb + col),
                (__attribute__((address_space(3))) void*)(&Bs[u << 3]), 16, 0, 0);
        }
        __syncthreads();
#pragma unroll
        for (int kq = 0; kq < 2; ++kq) {
            int slog = (kq << 2) | q4;
            bf16x8 af[4], bfv[4];
#pragma unroll
            for (int m = 0; m < 4; ++m) {
                int r = wr + (m << 4) + hr;
                af[m] = *(const bf16x8*)(&As[(r << 6) + ((slog ^ (r & 7)) << 3)]);
            }
#pragma unroll
            for (int n = 0; n < 4; ++n) {
                int r = wc + (n << 4) + hr;
                bfv[n] = *(const bf16x8*)(&Bs[(r << 6) + ((slog ^ (r & 7)) << 3)]);
            }
#pragma unroll
            for (int m = 0; m < 4; ++m)
#pragma unroll
                for (int n = 0; n < 4; ++n)
                    acc[m][n] = __builtin_amdgcn_mfma_f32_16x16x32_bf16(af[m], bfv[n], acc[m][n], 0, 0, 0);
        }
    }

    int rq = q4 << 2;
    int cl = hr;
#pragma unroll
    for (int n = 0; n < 4; ++n) {
        int col = wc + (n << 4) + cl;
        float bv = (ks == 0) ? bias[(size_t)e * N + n0 + col] : 0.0f;
#pragma unroll
        for (int m = 0; m < 4; ++m) {
#pragma unroll
            for (int r = 0; r < 4; ++r) {
                int row = wr + (m << 4) + rq + r;
                C[(size_t)(row0 + row) * N + n0 + col] = f2bf(acc[m][n][r] + bv);
            }
        }
    }
}

// x_out[t] = p0*(Oa[r0]+Ob[r0]) + p1*(Oa[r1]+Ob[r1])  (R6/R15-proven)
__global__ __launch_bounds__(256) void combine_kernel(
    const unsigned short* __restrict__ Oa, const unsigned short* __restrict__ Ob,
    const int* __restrict__ tok_e, const int* __restrict__ tok_slot,
    const float* __restrict__ tok_p, const int* __restrict__ poff,
    float* __restrict__ xout)
{
    int t = blockIdx.x;
    int e0 = tok_e[2 * t], e1 = tok_e[2 * t + 1];
    int r0 = poff[e0] + tok_slot[2 * t];
    int r1 = poff[e1] + tok_slot[2 * t + 1];
    float p0 = tok_p[2 * t], p1 = tok_p[2 * t + 1];
    int c = threadIdx.x << 2;
    u16x4 a0 = *(const u16x4*)(Oa + (size_t)r0 * DOUT + c);
    u16x4 a1 = *(const u16x4*)(Ob + (size_t)r0 * DOUT + c);
    u16x4 b0 = *(const u16x4*)(Oa + (size_t)r1 * DOUT + c);
    u16x4 b1 = *(const u16x4*)(Ob + (size_t)r1 * DOUT + c);
    f32x4 r;
#pragma unroll
    for (int j = 0; j < 4; ++j)
        r[j] = p0 * (bf2f(a0[j]) + bf2f(a1[j])) + p1 * (bf2f(b0[j]) + bf2f(b1[j]));
    *(f32x4*)(xout + (size_t)t * DOUT + c) = r;
}

extern "C" void kernel_launch(void* const* d_in, const int* in_sizes, int n_in,
                              void* d_out, int out_size, void* d_ws, size_t ws_size,
                              hipStream_t stream)
{
    const float* x     = (const float*)d_in[0];
    const float* noise = (const float*)d_in[1];
    const float* gw    = (const float*)d_in[2];
    const float* gb    = (const float*)d_in[3];
    const float* nw    = (const float*)d_in[4];
    const float* nb    = (const float*)d_in[5];
    const float* w1    = (const float*)d_in[6];
    const float* b1    = (const float*)d_in[7];
    const float* w2    = (const float*)d_in[8];
    const float* b2    = (const float*)d_in[9];
    float* xout = (float*)d_out;
    float* wout = xout + (size_t)T_TOK * DOUT;

    char* ws = (char*)d_ws;
    int*   cnt      = (int*)(ws + 0);
    int*   poff     = (int*)(ws + 256);
    int*   t2e      = (int*)(ws + 512);
    int*   trow     = (int*)(ws + 1024);
    int*   tok_e    = (int*)(ws + 2048);
    int*   tok_slot = (int*)(ws + 34816);
    float* tok_p    = (float*)(ws + 67584);
    size_t oXg = 104448;                                  // 256-aligned
    unsigned short* Xg  = (unsigned short*)(ws + oXg);
    size_t oH  = oXg + (size_t)RCAP * DIN * 2;            // Xg 18.9 MB
    unsigned short* H   = (unsigned short*)(ws + oH);     // H 75.5 MB
    size_t oW1 = oH + (size_t)RCAP * HDIM * 2;
    unsigned short* W1t = (unsigned short*)(ws + oW1);    // 67.1 MB
    size_t oW2 = oW1 + (size_t)NEXP * HDIM * DIN * 2;
    unsigned short* W2t = (unsigned short*)(ws + oW2);    // 67.1 MB
    // Oa/Ob alias W1t (dead after GEMM1): 2 x 18.9 MB <= 67.1 MB
    unsigned short* Oa = W1t;
    unsigned short* Ob = W1t + (size_t)RCAP * DOUT;
    // total ~228.6 MB

    gating_kernel<<<T_TOK, 64, 0, stream>>>(x, noise, gw, gb, nw, nb,
                                            wout, tok_e, tok_p);
    scan_kernel<<<NEXP, 256, 0, stream>>>(tok_e, tok_slot, cnt);
    prefix_kernel<<<1, 1, 0, stream>>>(cnt, poff, t2e, trow);
    gather_kernel<<<2 * T_TOK, 256, 0, stream>>>(x, tok_e, tok_slot, poff, Xg);
    convw2x_kernel<<<dim3(NEXP, 2048), 256, 0, stream>>>(w1, W1t, w2, W2t);
    // GEMM1: H = relu(Xg @ W1[e] + b1), 128x256 tiles
    gemm1_wide_kernel<<<MT128 * 16, 512, 0, stream>>>(
        Xg, W1t, H, b1, t2e, trow);
    // GEMM2 split-K=2: Oa = H[:,:2048]@W2[:2048]+b2 ; Ob = H[:,2048:]@W2[2048:]
    gemm2_sk_kernel<<<MT128 * 16, 256, 0, stream>>>(
        H, W2t, Oa, Ob, b2, t2e, trow);
    combine_kernel<<<T_TOK, 256, 0, stream>>>(Oa, Ob, tok_e, tok_slot, tok_p, poff, xout);
}

// Round 17
// 332.623 us; speedup vs baseline: 1.0422x; 1.0422x over previous
//
#include <hip/hip_runtime.h>

#define T_TOK 4096
#define DIN   1024
#define DOUT  1024
#define NEXP  8
#define HDIM  4096
#define RCAP  9216       // 8192 rows + 8 experts x <=127 pad (128-aligned)
#define MT128 80

typedef float f32x4 __attribute__((ext_vector_type(4)));
typedef short bf16x8 __attribute__((ext_vector_type(8)));
typedef unsigned short u16x4 __attribute__((ext_vector_type(4)));
typedef unsigned short u16x8 __attribute__((ext_vector_type(8)));

__device__ __forceinline__ float bf2f(unsigned short u) {
    union { unsigned int i; float f; } v; v.i = ((unsigned int)u) << 16; return v.f;
}
__device__ __forceinline__ unsigned short f2bf(float f) {
    union { unsigned int i; float f; } v; v.f = f;
    unsigned int r = v.i + 0x7FFFu + ((v.i >> 16) & 1u);
    return (unsigned short)(r >> 16);
}

// One wave per token: fp64 gating dots, softplus, top-2, softmax. NO atomics.
__global__ __launch_bounds__(64) void gating_kernel(
    const float* __restrict__ x, const float* __restrict__ noise,
    const float* __restrict__ gw, const float* __restrict__ gb,
    const float* __restrict__ nw, const float* __restrict__ nb,
    float* __restrict__ wout,
    int* __restrict__ tok_e, float* __restrict__ tok_p)
{
    int t = blockIdx.x;
    int lane = threadIdx.x;
    const float* xr = x + (size_t)t * DIN;
    double ag[NEXP], an[NEXP];
#pragma unroll
    for (int e = 0; e < NEXP; ++e) { ag[e] = 0.0; an[e] = 0.0; }
    for (int d = lane; d < DIN; d += 64) {
        double xv = (double)xr[d];
        const f32x4* g4 = (const f32x4*)(gw + (size_t)d * NEXP);
        const f32x4* n4 = (const f32x4*)(nw + (size_t)d * NEXP);
        f32x4 ga = g4[0], gbv = g4[1], na = n4[0], nbv = n4[1];
#pragma unroll
        for (int j = 0; j < 4; ++j) {
            ag[j]     += xv * (double)ga[j];
            ag[4 + j] += xv * (double)gbv[j];
            an[j]     += xv * (double)na[j];
            an[4 + j] += xv * (double)nbv[j];
        }
    }
#pragma unroll
    for (int e = 0; e < NEXP; ++e) {
        double g = ag[e], n = an[e];
#pragma unroll
        for (int m = 32; m > 0; m >>= 1) { g += __shfl_xor(g, m); n += __shfl_xor(n, m); }
        ag[e] = g; an[e] = n;
    }
    double lg[NEXP];
#pragma unroll
    for (int e = 0; e < NEXP; ++e) {
        double z = an[e] + (double)nb[e];
        double sp = fmax(z, 0.0) + log1p(exp(-fabs(z)));
        lg[e] = ag[e] + (double)gb[e] + (double)noise[(size_t)t * NEXP + e] * sp;
    }
    int i0 = 0; double v0 = lg[0];
#pragma unroll
    for (int e = 1; e < NEXP; ++e) if (lg[e] > v0) { v0 = lg[e]; i0 = e; }
    int i1 = -1; double v1 = -1.0e300;
#pragma unroll
    for (int e = 0; e < NEXP; ++e) if (e != i0 && lg[e] > v1) { v1 = lg[e]; i1 = e; }
    double d1 = exp(v1 - v0);
    float p0 = (float)(1.0 / (1.0 + d1));
    float p1 = (float)(d1 / (1.0 + d1));
    if (lane < NEXP) {
        float wv = (lane == i0) ? p0 : ((lane == i1) ? p1 : 0.0f);
        wout[(size_t)t * NEXP + lane] = wv;
    }
    if (lane == 0) {
        tok_e[2 * t] = i0;     tok_e[2 * t + 1] = i1;
        tok_p[2 * t] = p0;     tok_p[2 * t + 1] = p1;
    }
}

// Deterministic slot assignment: block e scans tok_e[] in sequential order.
__global__ __launch_bounds__(256) void scan_kernel(
    const int* __restrict__ tok_e, int* __restrict__ tok_slot, int* __restrict__ cnt)
{
    __shared__ int wsum[4];
    int e = blockIdx.x;
    int tid = threadIdx.x;
    int wv = tid >> 6;
    int lane = tid & 63;
    int base = 0;
    for (int c = 0; c < 2 * T_TOK; c += 256) {
        int i = c + tid;
        int m = (tok_e[i] == e) ? 1 : 0;
        unsigned long long bal = __ballot(m);
        int before = __popcll(bal & ((1ull << lane) - 1ull));
        if (lane == 0) wsum[wv] = __popcll(bal);
        __syncthreads();
        int woff = 0;
#pragma unroll
        for (int w = 0; w < 4; ++w) if (w < wv) woff += wsum[w];
        if (m) tok_slot[i] = base + woff + before;
        int tot = wsum[0] + wsum[1] + wsum[2] + wsum[3];
        __syncthreads();
        base += tot;
    }
    if (tid == 0) cnt[e] = base;
}

// 128-row-aligned per-expert offsets + 128-row tile map.
__global__ void prefix_kernel(const int* __restrict__ cnt, int* __restrict__ poff,
                              int* __restrict__ t2e, int* __restrict__ trow)
{
    if (threadIdx.x != 0 || blockIdx.x != 0) return;
    int base = 0, a = 0;
    for (int e = 0; e < NEXP; ++e) {
        poff[e] = base;
        int c = cnt[e];
        int nt = (c + 127) >> 7;
        for (int i = 0; i < nt; ++i) { t2e[a] = e; trow[a] = base + (i << 7); ++a; }
        base += nt << 7;
    }
    for (; a < MT128; ++a) { t2e[a] = -1; trow[a] = 0; }
}

// Gather: 2048 blocks x 4 rows (one row per wave), 4 coalesced passes/row.
// Coarsened from 8192 tiny blocks (launch-overhead-bound at 3.5 TB/s).
__global__ __launch_bounds__(256) void gather_kernel(
    const float* __restrict__ x, const int* __restrict__ tok_e,
    const int* __restrict__ tok_slot, const int* __restrict__ poff,
    unsigned short* __restrict__ Xg)
{
    int g = (blockIdx.x << 2) + (threadIdx.x >> 6);   // 0..8191
    int lane = threadIdx.x & 63;
    int t = g >> 1, k = g & 1;
    int e = tok_e[2 * t + k];
    int row = poff[e] + tok_slot[2 * t + k];
    const float* src = x + (size_t)t * DIN;
    unsigned short* dst = Xg + (size_t)row * DIN;
#pragma unroll
    for (int p = 0; p < 4; ++p) {
        int c = (p << 8) + (lane << 2);
        f32x4 v = *(const f32x4*)(src + c);
        u16x4 o;
#pragma unroll
        for (int j = 0; j < 4; ++j) o[j] = f2bf(v[j]);
        *(u16x4*)(dst + c) = o;
    }
}

// Transpose+convert both W1 and W2 in ONE dispatch (R14-proven, ~5.7 TB/s —
// at the HBM ceiling for its 402 MB of traffic).
__global__ __launch_bounds__(256) void convw2x_kernel(
    const float* __restrict__ w1, unsigned short* __restrict__ W1t,
    const float* __restrict__ w2, unsigned short* __restrict__ W2t)
{
    __shared__ float tile[64][65];
    int e = blockIdx.x;
    int idx = blockIdx.y;
    const float* W; unsigned short* Wt; int K, N, k0, n0;
    if (idx < 1024) {
        W = w1; Wt = W1t; K = DIN; N = HDIM;
        k0 = (idx >> 6) << 6; n0 = (idx & 63) << 6;
    } else {
        int i2 = idx - 1024;
        W = w2; Wt = W2t; K = HDIM; N = DOUT;
        k0 = (i2 >> 4) << 6; n0 = (i2 & 15) << 6;
    }
    int tid = threadIdx.x;
    const float* src = W + ((size_t)e * K + k0) * N + n0;
    int r = tid >> 4, c4 = (tid & 15) << 2;
#pragma unroll
    for (int i = 0; i < 4; ++i) {
        f32x4 v = *(const f32x4*)(src + (size_t)(r + (i << 4)) * N + c4);
        *(f32x4*)(&tile[r + (i << 4)][c4]) = v;
    }
    __syncthreads();
    unsigned short* dst = Wt + ((size_t)e * N + n0) * K + k0;
#pragma unroll
    for (int i = 0; i < 2; ++i) {
        int u = (i << 8) + tid;          // 512 units of 16B
        int n = u >> 3, kk = (u & 7) << 3;
        u16x8 o;
#pragma unroll
        for (int q = 0; q < 8; ++q) o[q] = f2bf(tile[kk + q][n]);
        *(u16x8*)(dst + (size_t)n * K + kk) = o;
    }
}

// GEMM1: 128x256 tile, BK=64, 8 waves (R14-proven), single-buffer 48KB LDS,
// 2-barrier loop, BK=64 swizzle LDS[r*64 + ((k>>3 ^ (r&7))<<3) + (k&7)].
__global__ __launch_bounds__(512, 4) void gemm1_wide_kernel(
    const unsigned short* __restrict__ A,
    const unsigned short* __restrict__ Bt,
    unsigned short* __restrict__ C,
    const float* __restrict__ bias,
    const int* __restrict__ t2e, const int* __restrict__ trow)
{
    const int lda = DIN, ldb = DIN, N = HDIM;
    int cpx = gridDim.x >> 3;
    int wg = ((blockIdx.x & 7) * cpx) + (blockIdx.x >> 3);
    int tileid = wg >> 4;
    int nb = wg & 15;
    int e = t2e[tileid];
    if (e < 0) return;
    int row0 = trow[tileid];
    int n0 = nb << 8;

    __shared__ __align__(16) unsigned short As[128 * 64];
    __shared__ __align__(16) unsigned short Bs[256 * 64];

    int tid = threadIdx.x;
    int lane = tid & 63;
    int wv = tid >> 6;
    int wr = (wv >> 2) << 6;
    int wc = (wv & 3) << 6;

    const unsigned short* Ab = A + (size_t)row0 * lda;
    const unsigned short* Bb = Bt + ((size_t)e * N + n0) * ldb;

    f32x4 acc[4][4] = {};
    int hr = lane & 15;
    int q4 = lane >> 4;

    for (int kt = 0; kt < 16; ++kt) {
        __syncthreads();
        int kb = kt << 6;
#pragma unroll
        for (int i = 0; i < 2; ++i) {
            int u = (i << 9) + tid;
            int r = u >> 3, sp = u & 7;
            int col = ((sp ^ (r & 7)) << 3);
            __builtin_amdgcn_global_load_lds(
                (const __attribute__((address_space(1))) void*)(Ab + (size_t)r * lda + kb + col),
                (__attribute__((address_space(3))) void*)(&As[u << 3]), 16, 0, 0);
        }
#pragma unroll
        for (int i = 0; i < 4; ++i) {
            int u = (i << 9) + tid;
            int r = u >> 3, sp = u & 7;
            int col = ((sp ^ (r & 7)) << 3);
            __builtin_amdgcn_global_load_lds(
                (const __attribute__((address_space(1))) void*)(Bb + (size_t)r * ldb + kb + col),
                (__attribute__((address_space(3))) void*)(&Bs[u << 3]), 16, 0, 0);
        }
        __syncthreads();
#pragma unroll
        for (int kq = 0; kq < 2; ++kq) {
            int slog = (kq << 2) | q4;
            bf16x8 af[4], bfv[4];
#pragma unroll
            for (int m = 0; m < 4; ++m) {
                int r = wr + (m << 4) + hr;
                af[m] = *(const bf16x8*)(&As[(r << 6) + ((slog ^ (r & 7)) << 3)]);
            }
#pragma unroll
            for (int n = 0; n < 4; ++n) {
                int r = wc + (n << 4) + hr;
                bfv[n] = *(const bf16x8*)(&Bs[(r << 6) + ((slog ^ (r & 7)) << 3)]);
            }
#pragma unroll
            for (int m = 0; m < 4; ++m)
#pragma unroll
                for (int n = 0; n < 4; ++n)
                    acc[m][n] = __builtin_amdgcn_mfma_f32_16x16x32_bf16(af[m], bfv[n], acc[m][n], 0, 0, 0);
        }
    }

    int rq = q4 << 2;
    int cl = hr;
#pragma unroll
    for (int n = 0; n < 4; ++n) {
        int col = wc + (n << 4) + cl;
        float bv = bias[(size_t)e * N + n0 + col];
#pragma unroll
        for (int m = 0; m < 4; ++m) {
#pragma unroll
            for (int r = 0; r < 4; ++r) {
                int row = wr + (m << 4) + rq + r;
                float v = acc[m][n][r] + bv;
                v = fmaxf(v, 0.0f);
                C[(size_t)(row0 + row) * N + n0 + col] = f2bf(v);
            }
        }
    }
}

// GEMM2: R14-proven 128x128 BK=64 single-buffer kernel (split-K reverted:
// R16 showed it null on GEMM time and +5us in combine).
__global__ __launch_bounds__(256, 4) void gemm64_kernel(
    const unsigned short* __restrict__ A, int lda,
    const unsigned short* __restrict__ Bt, int ldb, int N, int KLEN,
    unsigned short* __restrict__ C,
    const float* __restrict__ bias,
    const int* __restrict__ t2e, const int* __restrict__ trow,
    int nbshift, int relu)
{
    int nwg = gridDim.x;
    int cpx = nwg >> 3;
    int wg = ((blockIdx.x & 7) * cpx) + (blockIdx.x >> 3);
    int tileid = wg >> nbshift;
    int nb = wg & ((1 << nbshift) - 1);

    int e = t2e[tileid];
    if (e < 0) return;
    int row0 = trow[tileid];
    int n0 = nb << 7;

    __shared__ __align__(16) unsigned short As[128 * 64];
    __shared__ __align__(16) unsigned short Bs[128 * 64];

    int tid = threadIdx.x;
    int lane = tid & 63;
    int wv = tid >> 6;
    int wr = (wv >> 1) << 6;
    int wc = (wv & 1) << 6;

    const unsigned short* Ab = A + (size_t)row0 * lda;
    const unsigned short* Bb = Bt + ((size_t)e * N + n0) * ldb;

    f32x4 acc[4][4] = {};

    int sr_lo = tid >> 3;
    int sp = tid & 7;
    int hr = lane & 15;
    int q4 = lane >> 4;

    int nkt = KLEN >> 6;
    for (int kt = 0; kt < nkt; ++kt) {
        __syncthreads();
        int kb = kt << 6;
#pragma unroll
        for (int i = 0; i < 4; ++i) {
            int r = (i << 5) + sr_lo;
            int col = ((sp ^ (r & 7)) << 3);
            int u = (i << 8) + tid;
            __builtin_amdgcn_global_load_lds(
                (const __attribute__((address_space(1))) void*)(Ab + (size_t)r * lda + kb + col),
                (__attribute__((address_space(3))) void*)(&As[u << 3]), 16, 0, 0);
            __builtin_amdgcn_global_load_lds(
                (const __attribute__((address_space(1))) void*)(Bb + (size_t)r * ldb + kb + col),
                (__attribute__((address_space(3))) void*)(&Bs[u << 3]), 16, 0, 0);
        }
        __syncthreads();
#pragma unroll
        for (int kq = 0; kq < 2; ++kq) {
            int slog = (kq << 2) | q4;
            bf16x8 af[4], bfv[4];
#pragma unroll
            for (int m = 0; m < 4; ++m) {
                int r = wr + (m << 4) + hr;
                af[m] = *(const bf16x8*)(&As[(r << 6) + ((slog ^ (r & 7)) << 3)]);
            }
#pragma unroll
            for (int n = 0; n < 4; ++n) {
                int r = wc + (n << 4) + hr;
                bfv[n] = *(const bf16x8*)(&Bs[(r << 6) + ((slog ^ (r & 7)) << 3)]);
            }
#pragma unroll
            for (int m = 0; m < 4; ++m)
#pragma unroll
                for (int n = 0; n < 4; ++n)
                    acc[m][n] = __builtin_amdgcn_mfma_f32_16x16x32_bf16(af[m], bfv[n], acc[m][n], 0, 0, 0);
        }
    }

    int rq = q4 << 2;
    int cl = hr;
#pragma unroll
    for (int n = 0; n < 4; ++n) {
        int col = wc + (n << 4) + cl;
        float bv = bias[(size_t)e * N + n0 + col];
#pragma unroll
        for (int m = 0; m < 4; ++m) {
#pragma unroll
            for (int r = 0; r < 4; ++r) {
                int row = wr + (m << 4) + rq + r;
                float v = acc[m][n][r] + bv;
                if (relu) v = fmaxf(v, 0.0f);
                C[(size_t)(row0 + row) * N + n0 + col] = f2bf(v);
            }
        }
    }
}

// x_out[t] = p0*O[row0] + p1*O[row1]
__global__ __launch_bounds__(256) void combine_kernel(
    const unsigned short* __restrict__ O, const int* __restrict__ tok_e,
    const int* __restrict__ tok_slot, const float* __restrict__ tok_p,
    const int* __restrict__ poff, float* __restrict__ xout)
{
    int t = blockIdx.x;
    int e0 = tok_e[2 * t], e1 = tok_e[2 * t + 1];
    int r0 = poff[e0] + tok_slot[2 * t];
    int r1 = poff[e1] + tok_slot[2 * t + 1];
    float p0 = tok_p[2 * t], p1 = tok_p[2 * t + 1];
    int c = threadIdx.x << 2;
    u16x4 a = *(const u16x4*)(O + (size_t)r0 * DOUT + c);
    u16x4 b = *(const u16x4*)(O + (size_t)r1 * DOUT + c);
    f32x4 r;
#pragma unroll
    for (int j = 0; j < 4; ++j) r[j] = p0 * bf2f(a[j]) + p1 * bf2f(b[j]);
    *(f32x4*)(xout + (size_t)t * DOUT + c) = r;
}

extern "C" void kernel_launch(void* const* d_in, const int* in_sizes, int n_in,
                              void* d_out, int out_size, void* d_ws, size_t ws_size,
                              hipStream_t stream)
{
    const float* x     = (const float*)d_in[0];
    const float* noise = (const float*)d_in[1];
    const float* gw    = (const float*)d_in[2];
    const float* gb    = (const float*)d_in[3];
    const float* nw    = (const float*)d_in[4];
    const float* nb    = (const float*)d_in[5];
    const float* w1    = (const float*)d_in[6];
    const float* b1    = (const float*)d_in[7];
    const float* w2    = (const float*)d_in[8];
    const float* b2    = (const float*)d_in[9];
    float* xout = (float*)d_out;
    float* wout = xout + (size_t)T_TOK * DOUT;

    char* ws = (char*)d_ws;
    int*   cnt      = (int*)(ws + 0);
    int*   poff     = (int*)(ws + 256);
    int*   t2e      = (int*)(ws + 512);
    int*   trow     = (int*)(ws + 1024);
    int*   tok_e    = (int*)(ws + 2048);
    int*   tok_slot = (int*)(ws + 34816);
    float* tok_p    = (float*)(ws + 67584);
    size_t oXg = 104448;                                  // 256-aligned
    unsigned short* Xg  = (unsigned short*)(ws + oXg);
    unsigned short* O   = Xg;                             // O aliases Xg (dead after GEMM1)
    size_t oH  = oXg + (size_t)RCAP * DIN * 2;            // Xg 18.9 MB
    unsigned short* H   = (unsigned short*)(ws + oH);     // H 75.5 MB
    size_t oW1 = oH + (size_t)RCAP * HDIM * 2;
    unsigned short* W1t = (unsigned short*)(ws + oW1);    // 67.1 MB
    size_t oW2 = oW1 + (size_t)NEXP * HDIM * DIN * 2;
    unsigned short* W2t = (unsigned short*)(ws + oW2);    // 67.1 MB
    // total ~228.6 MB

    gating_kernel<<<T_TOK, 64, 0, stream>>>(x, noise, gw, gb, nw, nb,
                                            wout, tok_e, tok_p);
    scan_kernel<<<NEXP, 256, 0, stream>>>(tok_e, tok_slot, cnt);
    prefix_kernel<<<1, 1, 0, stream>>>(cnt, poff, t2e, trow);
    gather_kernel<<<2 * T_TOK / 4, 256, 0, stream>>>(x, tok_e, tok_slot, poff, Xg);
    convw2x_kernel<<<dim3(NEXP, 2048), 256, 0, stream>>>(w1, W1t, w2, W2t);
    // GEMM1: H = relu(Xg @ W1[e] + b1), 128x256 tiles
    gemm1_wide_kernel<<<MT128 * 16, 512, 0, stream>>>(
        Xg, W1t, H, b1, t2e, trow);
    // GEMM2: O = H @ W2[e] + b2 (R14 kernel, split-K reverted)
    gemm64_kernel<<<MT128 * 8, 256, 0, stream>>>(
        H, HDIM, W2t, HDIM, DOUT, HDIM, O, b2, t2e, trow, 3, 0);
    combine_kernel<<<T_TOK, 256, 0, stream>>>(O, tok_e, tok_slot, tok_p, poff, xout);
}

// Round 18
// 332.449 us; speedup vs baseline: 1.0427x; 1.0005x over previous
//
#include <hip/hip_runtime.h>

#define T_TOK 4096
#define DIN   1024
#define DOUT  1024
#define NEXP  8
#define HDIM  4096
#define RCAP  9216       // 8192 rows + 8 experts x <=127 pad (128-aligned)
#define MT128 80

typedef float f32x4 __attribute__((ext_vector_type(4)));
typedef short bf16x8 __attribute__((ext_vector_type(8)));
typedef unsigned short u16x4 __attribute__((ext_vector_type(4)));
typedef unsigned short u16x8 __attribute__((ext_vector_type(8)));

__device__ __forceinline__ float bf2f(unsigned short u) {
    union { unsigned int i; float f; } v; v.i = ((unsigned int)u) << 16; return v.f;
}
__device__ __forceinline__ unsigned short f2bf(float f) {
    union { unsigned int i; float f; } v; v.f = f;
    unsigned int r = v.i + 0x7FFFu + ((v.i >> 16) & 1u);
    return (unsigned short)(r >> 16);
}

// Gating: 4 independent waves per 256-thr block (one token each); fp64 dots,
// softplus, top-2, softmax. NO atomics (scan assigns slots deterministically).
__global__ __launch_bounds__(256) void gating_kernel(
    const float* __restrict__ x, const float* __restrict__ noise,
    const float* __restrict__ gw, const float* __restrict__ gb,
    const float* __restrict__ nw, const float* __restrict__ nb,
    float* __restrict__ wout,
    int* __restrict__ tok_e, float* __restrict__ tok_p)
{
    int t = (blockIdx.x << 2) + (threadIdx.x >> 6);
    int lane = threadIdx.x & 63;
    const float* xr = x + (size_t)t * DIN;
    double ag[NEXP], an[NEXP];
#pragma unroll
    for (int e = 0; e < NEXP; ++e) { ag[e] = 0.0; an[e] = 0.0; }
    for (int d = lane; d < DIN; d += 64) {
        double xv = (double)xr[d];
        const f32x4* g4 = (const f32x4*)(gw + (size_t)d * NEXP);
        const f32x4* n4 = (const f32x4*)(nw + (size_t)d * NEXP);
        f32x4 ga = g4[0], gbv = g4[1], na = n4[0], nbv = n4[1];
#pragma unroll
        for (int j = 0; j < 4; ++j) {
            ag[j]     += xv * (double)ga[j];
            ag[4 + j] += xv * (double)gbv[j];
            an[j]     += xv * (double)na[j];
            an[4 + j] += xv * (double)nbv[j];
        }
    }
#pragma unroll
    for (int e = 0; e < NEXP; ++e) {
        double g = ag[e], n = an[e];
#pragma unroll
        for (int m = 32; m > 0; m >>= 1) { g += __shfl_xor(g, m); n += __shfl_xor(n, m); }
        ag[e] = g; an[e] = n;
    }
    double lg[NEXP];
#pragma unroll
    for (int e = 0; e < NEXP; ++e) {
        double z = an[e] + (double)nb[e];
        double sp = fmax(z, 0.0) + log1p(exp(-fabs(z)));
        lg[e] = ag[e] + (double)gb[e] + (double)noise[(size_t)t * NEXP + e] * sp;
    }
    int i0 = 0; double v0 = lg[0];
#pragma unroll
    for (int e = 1; e < NEXP; ++e) if (lg[e] > v0) { v0 = lg[e]; i0 = e; }
    int i1 = -1; double v1 = -1.0e300;
#pragma unroll
    for (int e = 0; e < NEXP; ++e) if (e != i0 && lg[e] > v1) { v1 = lg[e]; i1 = e; }
    double d1 = exp(v1 - v0);
    float p0 = (float)(1.0 / (1.0 + d1));
    float p1 = (float)(d1 / (1.0 + d1));
    if (lane < NEXP) {
        float wv = (lane == i0) ? p0 : ((lane == i1) ? p1 : 0.0f);
        wout[(size_t)t * NEXP + lane] = wv;
    }
    if (lane == 0) {
        tok_e[2 * t] = i0;     tok_e[2 * t + 1] = i1;
        tok_p[2 * t] = p0;     tok_p[2 * t + 1] = p1;
    }
}

// Deterministic slot assignment: block e scans tok_e[] in sequential order.
__global__ __launch_bounds__(256) void scan_kernel(
    const int* __restrict__ tok_e, int* __restrict__ tok_slot, int* __restrict__ cnt)
{
    __shared__ int wsum[4];
    int e = blockIdx.x;
    int tid = threadIdx.x;
    int wv = tid >> 6;
    int lane = tid & 63;
    int base = 0;
    for (int c = 0; c < 2 * T_TOK; c += 256) {
        int i = c + tid;
        int m = (tok_e[i] == e) ? 1 : 0;
        unsigned long long bal = __ballot(m);
        int before = __popcll(bal & ((1ull << lane) - 1ull));
        if (lane == 0) wsum[wv] = __popcll(bal);
        __syncthreads();
        int woff = 0;
#pragma unroll
        for (int w = 0; w < 4; ++w) if (w < wv) woff += wsum[w];
        if (m) tok_slot[i] = base + woff + before;
        int tot = wsum[0] + wsum[1] + wsum[2] + wsum[3];
        __syncthreads();
        base += tot;
    }
    if (tid == 0) cnt[e] = base;
}

// 128-row-aligned per-expert offsets + 128-row tile map.
__global__ void prefix_kernel(const int* __restrict__ cnt, int* __restrict__ poff,
                              int* __restrict__ t2e, int* __restrict__ trow)
{
    if (threadIdx.x != 0 || blockIdx.x != 0) return;
    int base = 0, a = 0;
    for (int e = 0; e < NEXP; ++e) {
        poff[e] = base;
        int c = cnt[e];
        int nt = (c + 127) >> 7;
        for (int i = 0; i < nt; ++i) { t2e[a] = e; trow[a] = base + (i << 7); ++a; }
        base += nt << 7;
    }
    for (; a < MT128; ++a) { t2e[a] = -1; trow[a] = 0; }
}

// Gather: 2048 blocks x 4 rows (one row per wave), 4 coalesced passes/row.
__global__ __launch_bounds__(256) void gather_kernel(
    const float* __restrict__ x, const int* __restrict__ tok_e,
    const int* __restrict__ tok_slot, const int* __restrict__ poff,
    unsigned short* __restrict__ Xg)
{
    int g = (blockIdx.x << 2) + (threadIdx.x >> 6);   // 0..8191
    int lane = threadIdx.x & 63;
    int t = g >> 1, k = g & 1;
    int e = tok_e[2 * t + k];
    int row = poff[e] + tok_slot[2 * t + k];
    const float* src = x + (size_t)t * DIN;
    unsigned short* dst = Xg + (size_t)row * DIN;
#pragma unroll
    for (int p = 0; p < 4; ++p) {
        int c = (p << 8) + (lane << 2);
        f32x4 v = *(const f32x4*)(src + c);
        u16x4 o;
#pragma unroll
        for (int j = 0; j < 4; ++j) o[j] = f2bf(v[j]);
        *(u16x4*)(dst + c) = o;
    }
}

// Transpose+convert both W1 and W2 in ONE dispatch (R14-proven, ~5.7 TB/s —
// at the HBM ceiling for its 402 MB of traffic).
__global__ __launch_bounds__(256) void convw2x_kernel(
    const float* __restrict__ w1, unsigned short* __restrict__ W1t,
    const float* __restrict__ w2, unsigned short* __restrict__ W2t)
{
    __shared__ float tile[64][65];
    int e = blockIdx.x;
    int idx = blockIdx.y;
    const float* W; unsigned short* Wt; int K, N, k0, n0;
    if (idx < 1024) {
        W = w1; Wt = W1t; K = DIN; N = HDIM;
        k0 = (idx >> 6) << 6; n0 = (idx & 63) << 6;
    } else {
        int i2 = idx - 1024;
        W = w2; Wt = W2t; K = HDIM; N = DOUT;
        k0 = (i2 >> 4) << 6; n0 = (i2 & 15) << 6;
    }
    int tid = threadIdx.x;
    const float* src = W + ((size_t)e * K + k0) * N + n0;
    int r = tid >> 4, c4 = (tid & 15) << 2;
#pragma unroll
    for (int i = 0; i < 4; ++i) {
        f32x4 v = *(const f32x4*)(src + (size_t)(r + (i << 4)) * N + c4);
        *(f32x4*)(&tile[r + (i << 4)][c4]) = v;
    }
    __syncthreads();
    unsigned short* dst = Wt + ((size_t)e * N + n0) * K + k0;
#pragma unroll
    for (int i = 0; i < 2; ++i) {
        int u = (i << 8) + tid;          // 512 units of 16B
        int n = u >> 3, kk = (u & 7) << 3;
        u16x8 o;
#pragma unroll
        for (int q = 0; q < 8; ++q) o[q] = f2bf(tile[kk + q][n]);
        *(u16x8*)(dst + (size_t)n * K + kk) = o;
    }
}

// GEMM1: 128x256 tile, BK=64, 8 waves (R14-proven), single-buffer 48KB LDS,
// 2-barrier loop, BK=64 swizzle LDS[r*64 + ((k>>3 ^ (r&7))<<3) + (k&7)].
__global__ __launch_bounds__(512, 4) void gemm1_wide_kernel(
    const unsigned short* __restrict__ A,
    const unsigned short* __restrict__ Bt,
    unsigned short* __restrict__ C,
    const float* __restrict__ bias,
    const int* __restrict__ t2e, const int* __restrict__ trow)
{
    const int lda = DIN, ldb = DIN, N = HDIM;
    int cpx = gridDim.x >> 3;
    int wg = ((blockIdx.x & 7) * cpx) + (blockIdx.x >> 3);
    int tileid = wg >> 4;
    int nb = wg & 15;
    int e = t2e[tileid];
    if (e < 0) return;
    int row0 = trow[tileid];
    int n0 = nb << 8;

    __shared__ __align__(16) unsigned short As[128 * 64];
    __shared__ __align__(16) unsigned short Bs[256 * 64];

    int tid = threadIdx.x;
    int lane = tid & 63;
    int wv = tid >> 6;
    int wr = (wv >> 2) << 6;
    int wc = (wv & 3) << 6;

    const unsigned short* Ab = A + (size_t)row0 * lda;
    const unsigned short* Bb = Bt + ((size_t)e * N + n0) * ldb;

    f32x4 acc[4][4] = {};
    int hr = lane & 15;
    int q4 = lane >> 4;

    for (int kt = 0; kt < 16; ++kt) {
        __syncthreads();
        int kb = kt << 6;
#pragma unroll
        for (int i = 0; i < 2; ++i) {
            int u = (i << 9) + tid;
            int r = u >> 3, sp = u & 7;
            int col = ((sp ^ (r & 7)) << 3);
            __builtin_amdgcn_global_load_lds(
                (const __attribute__((address_space(1))) void*)(Ab + (size_t)r * lda + kb + col),
                (__attribute__((address_space(3))) void*)(&As[u << 3]), 16, 0, 0);
        }
#pragma unroll
        for (int i = 0; i < 4; ++i) {
            int u = (i << 9) + tid;
            int r = u >> 3, sp = u & 7;
            int col = ((sp ^ (r & 7)) << 3);
            __builtin_amdgcn_global_load_lds(
                (const __attribute__((address_space(1))) void*)(Bb + (size_t)r * ldb + kb + col),
                (__attribute__((address_space(3))) void*)(&Bs[u << 3]), 16, 0, 0);
        }
        __syncthreads();
#pragma unroll
        for (int kq = 0; kq < 2; ++kq) {
            int slog = (kq << 2) | q4;
            bf16x8 af[4], bfv[4];
#pragma unroll
            for (int m = 0; m < 4; ++m) {
                int r = wr + (m << 4) + hr;
                af[m] = *(const bf16x8*)(&As[(r << 6) + ((slog ^ (r & 7)) << 3)]);
            }
#pragma unroll
            for (int n = 0; n < 4; ++n) {
                int r = wc + (n << 4) + hr;
                bfv[n] = *(const bf16x8*)(&Bs[(r << 6) + ((slog ^ (r & 7)) << 3)]);
            }
#pragma unroll
            for (int m = 0; m < 4; ++m)
#pragma unroll
                for (int n = 0; n < 4; ++n)
                    acc[m][n] = __builtin_amdgcn_mfma_f32_16x16x32_bf16(af[m], bfv[n], acc[m][n], 0, 0, 0);
        }
    }

    int rq = q4 << 2;
    int cl = hr;
#pragma unroll
    for (int n = 0; n < 4; ++n) {
        int col = wc + (n << 4) + cl;
        float bv = bias[(size_t)e * N + n0 + col];
#pragma unroll
        for (int m = 0; m < 4; ++m) {
#pragma unroll
            for (int r = 0; r < 4; ++r) {
                int row = wr + (m << 4) + rq + r;
                float v = acc[m][n][r] + bv;
                v = fmaxf(v, 0.0f);
                C[(size_t)(row0 + row) * N + n0 + col] = f2bf(v);
            }
        }
    }
}

// GEMM2: R14-proven 128x128 BK=64 single-buffer kernel.
__global__ __launch_bounds__(256, 4) void gemm64_kernel(
    const unsigned short* __restrict__ A, int lda,
    const unsigned short* __restrict__ Bt, int ldb, int N, int KLEN,
    unsigned short* __restrict__ C,
    const float* __restrict__ bias,
    const int* __restrict__ t2e, const int* __restrict__ trow,
    int nbshift, int relu)
{
    int nwg = gridDim.x;
    int cpx = nwg >> 3;
    int wg = ((blockIdx.x & 7) * cpx) + (blockIdx.x >> 3);
    int tileid = wg >> nbshift;
    int nb = wg & ((1 << nbshift) - 1);

    int e = t2e[tileid];
    if (e < 0) return;
    int row0 = trow[tileid];
    int n0 = nb << 7;

    __shared__ __align__(16) unsigned short As[128 * 64];
    __shared__ __align__(16) unsigned short Bs[128 * 64];

    int tid = threadIdx.x;
    int lane = tid & 63;
    int wv = tid >> 6;
    int wr = (wv >> 1) << 6;
    int wc = (wv & 1) << 6;

    const unsigned short* Ab = A + (size_t)row0 * lda;
    const unsigned short* Bb = Bt + ((size_t)e * N + n0) * ldb;

    f32x4 acc[4][4] = {};

    int sr_lo = tid >> 3;
    int sp = tid & 7;
    int hr = lane & 15;
    int q4 = lane >> 4;

    int nkt = KLEN >> 6;
    for (int kt = 0; kt < nkt; ++kt) {
        __syncthreads();
        int kb = kt << 6;
#pragma unroll
        for (int i = 0; i < 4; ++i) {
            int r = (i << 5) + sr_lo;
            int col = ((sp ^ (r & 7)) << 3);
            int u = (i << 8) + tid;
            __builtin_amdgcn_global_load_lds(
                (const __attribute__((address_space(1))) void*)(Ab + (size_t)r * lda + kb + col),
                (__attribute__((address_space(3))) void*)(&As[u << 3]), 16, 0, 0);
            __builtin_amdgcn_global_load_lds(
                (const __attribute__((address_space(1))) void*)(Bb + (size_t)r * ldb + kb + col),
                (__attribute__((address_space(3))) void*)(&Bs[u << 3]), 16, 0, 0);
        }
        __syncthreads();
#pragma unroll
        for (int kq = 0; kq < 2; ++kq) {
            int slog = (kq << 2) | q4;
            bf16x8 af[4], bfv[4];
#pragma unroll
            for (int m = 0; m < 4; ++m) {
                int r = wr + (m << 4) + hr;
                af[m] = *(const bf16x8*)(&As[(r << 6) + ((slog ^ (r & 7)) << 3)]);
            }
#pragma unroll
            for (int n = 0; n < 4; ++n) {
                int r = wc + (n << 4) + hr;
                bfv[n] = *(const bf16x8*)(&Bs[(r << 6) + ((slog ^ (r & 7)) << 3)]);
            }
#pragma unroll
            for (int m = 0; m < 4; ++m)
#pragma unroll
                for (int n = 0; n < 4; ++n)
                    acc[m][n] = __builtin_amdgcn_mfma_f32_16x16x32_bf16(af[m], bfv[n], acc[m][n], 0, 0, 0);
        }
    }

    int rq = q4 << 2;
    int cl = hr;
#pragma unroll
    for (int n = 0; n < 4; ++n) {
        int col = wc + (n << 4) + cl;
        float bv = bias[(size_t)e * N + n0 + col];
#pragma unroll
        for (int m = 0; m < 4; ++m) {
#pragma unroll
            for (int r = 0; r < 4; ++r) {
                int row = wr + (m << 4) + rq + r;
                float v = acc[m][n][r] + bv;
                if (relu) v = fmaxf(v, 0.0f);
                C[(size_t)(row0 + row) * N + n0 + col] = f2bf(v);
            }
        }
    }
}

// x_out[t] = p0*O[row0] + p1*O[row1]
__global__ __launch_bounds__(256) void combine_kernel(
    const unsigned short* __restrict__ O, const int* __restrict__ tok_e,
    const int* __restrict__ tok_slot, const float* __restrict__ tok_p,
    const int* __restrict__ poff, float* __restrict__ xout)
{
    int t = blockIdx.x;
    int e0 = tok_e[2 * t], e1 = tok_e[2 * t + 1];
    int r0 = poff[e0] + tok_slot[2 * t];
    int r1 = poff[e1] + tok_slot[2 * t + 1];
    float p0 = tok_p[2 * t], p1 = tok_p[2 * t + 1];
    int c = threadIdx.x << 2;
    u16x4 a = *(const u16x4*)(O + (size_t)r0 * DOUT + c);
    u16x4 b = *(const u16x4*)(O + (size_t)r1 * DOUT + c);
    f32x4 r;
#pragma unroll
    for (int j = 0; j < 4; ++j) r[j] = p0 * bf2f(a[j]) + p1 * bf2f(b[j]);
    *(f32x4*)(xout + (size_t)t * DOUT + c) = r;
}

extern "C" void kernel_launch(void* const* d_in, const int* in_sizes, int n_in,
                              void* d_out, int out_size, void* d_ws, size_t ws_size,
                              hipStream_t stream)
{
    const float* x     = (const float*)d_in[0];
    const float* noise = (const float*)d_in[1];
    const float* gw    = (const float*)d_in[2];
    const float* gb    = (const float*)d_in[3];
    const float* nw    = (const float*)d_in[4];
    const float* nb    = (const float*)d_in[5];
    const float* w1    = (const float*)d_in[6];
    const float* b1    = (const float*)d_in[7];
    const float* w2    = (const float*)d_in[8];
    const float* b2    = (const float*)d_in[9];
    float* xout = (float*)d_out;
    float* wout = xout + (size_t)T_TOK * DOUT;

    char* ws = (char*)d_ws;
    int*   cnt      = (int*)(ws + 0);
    int*   poff     = (int*)(ws + 256);
    int*   t2e      = (int*)(ws + 512);
    int*   trow     = (int*)(ws + 1024);
    int*   tok_e    = (int*)(ws + 2048);
    int*   tok_slot = (int*)(ws + 34816);
    float* tok_p    = (float*)(ws + 67584);
    size_t oXg = 104448;                                  // 256-aligned
    unsigned short* Xg  = (unsigned short*)(ws + oXg);
    unsigned short* O   = Xg;                             // O aliases Xg (dead after GEMM1)
    size_t oH  = oXg + (size_t)RCAP * DIN * 2;            // Xg 18.9 MB
    unsigned short* H   = (unsigned short*)(ws + oH);     // H 75.5 MB
    size_t oW1 = oH + (size_t)RCAP * HDIM * 2;
    unsigned short* W1t = (unsigned short*)(ws + oW1);    // 67.1 MB
    size_t oW2 = oW1 + (size_t)NEXP * HDIM * DIN * 2;
    unsigned short* W2t = (unsigned short*)(ws + oW2);    // 67.1 MB
    // total ~228.6 MB

    gating_kernel<<<T_TOK / 4, 256, 0, stream>>>(x, noise, gw, gb, nw, nb,
                                                 wout, tok_e, tok_p);
    scan_kernel<<<NEXP, 256, 0, stream>>>(tok_e, tok_slot, cnt);
    prefix_kernel<<<1, 1, 0, stream>>>(cnt, poff, t2e, trow);
    gather_kernel<<<2 * T_TOK / 4, 256, 0, stream>>>(x, tok_e, tok_slot, poff, Xg);
    convw2x_kernel<<<dim3(NEXP, 2048), 256, 0, stream>>>(w1, W1t, w2, W2t);
    // GEMM1: H = relu(Xg @ W1[e] + b1), 128x256 tiles
    gemm1_wide_kernel<<<MT128 * 16, 512, 0, stream>>>(
        Xg, W1t, H, b1, t2e, trow);
    // GEMM2: O = H @ W2[e] + b2
    gemm64_kernel<<<MT128 * 8, 256, 0, stream>>>(
        H, HDIM, W2t, HDIM, DOUT, HDIM, O, b2, t2e, trow, 3, 0);
    combine_kernel<<<T_TOK, 256, 0, stream>>>(O, tok_e, tok_slot, tok_p, poff, xout);
}